// Round 1
// baseline (4608.842 us; speedup 1.0000x reference)
//
#include <hip/hip_runtime.h>

#define CCH 64      // channels
#define KOFF 27     // kernel offsets
#define NV 32       // voxels per wave
#define EPSV 1e-5f

// ---------------------------------------------------------------------------
// Gathered conv: out[n][d] = sum_k sum_c fin[nbr[n,k]][c] * W[k][c][d] + bias[d]
// One wave handles NV voxels; lane = d. Weight column W[k][:,d] held in VGPRs,
// feature rows are wave-uniform -> scalar loads (readfirstlane on row index).
// ---------------------------------------------------------------------------
__global__ __launch_bounds__(256, 3)
void conv_kernel(const float* __restrict__ fin, const int* __restrict__ nbr,
                 const float* __restrict__ W, const float* __restrict__ bias,
                 float* __restrict__ out, int N)
{
    const int lane = threadIdx.x & 63;
    const int wv   = threadIdx.x >> 6;
    const int n0   = blockIdx.x * (4 * NV) + wv * NV;
    if (n0 >= N) return;   // wave-uniform early-out, no __syncthreads in kernel

    float acc[NV];
    const float bval = bias[lane];
#pragma unroll
    for (int j = 0; j < NV; ++j) acc[j] = 0.f;

    for (int k = 0; k < KOFF; ++k) {
        // stage W[k][c][lane] for all c into registers (coalesced loads)
        float w[CCH];
        const float* Wk = W + (size_t)k * CCH * CCH + lane;
#pragma unroll
        for (int c = 0; c < CCH; ++c) w[c] = Wk[c * CCH];

#pragma unroll 1
        for (int n4 = 0; n4 < NV; n4 += 4) {
            const int nb = n0 + n4;
            int r0 = (nb + 0 < N) ? nbr[(size_t)(nb + 0) * KOFF + k] : 0;
            int r1 = (nb + 1 < N) ? nbr[(size_t)(nb + 1) * KOFF + k] : 0;
            int r2 = (nb + 2 < N) ? nbr[(size_t)(nb + 2) * KOFF + k] : 0;
            int r3 = (nb + 3 < N) ? nbr[(size_t)(nb + 3) * KOFF + k] : 0;
            // rows are wave-uniform by construction: force scalar loads
            r0 = __builtin_amdgcn_readfirstlane(r0);
            r1 = __builtin_amdgcn_readfirstlane(r1);
            r2 = __builtin_amdgcn_readfirstlane(r2);
            r3 = __builtin_amdgcn_readfirstlane(r3);
            const float* f0 = fin + (size_t)r0 * CCH;
            const float* f1 = fin + (size_t)r1 * CCH;
            const float* f2 = fin + (size_t)r2 * CCH;
            const float* f3 = fin + (size_t)r3 * CCH;
#pragma unroll
            for (int c = 0; c < CCH; ++c) {
                const float wc = w[c];
                acc[n4 + 0] = fmaf(f0[c], wc, acc[n4 + 0]);
                acc[n4 + 1] = fmaf(f1[c], wc, acc[n4 + 1]);
                acc[n4 + 2] = fmaf(f2[c], wc, acc[n4 + 2]);
                acc[n4 + 3] = fmaf(f3[c], wc, acc[n4 + 3]);
            }
        }
    }

#pragma unroll
    for (int j = 0; j < NV; ++j) {
        const int n = n0 + j;
        if (n < N) out[(size_t)n * CCH + lane] = acc[j] + bval;
    }
}

// ---------------------------------------------------------------------------
// Per-channel sum and sum-of-squares over N rows. sums[0:64]=sum, [64:128]=sumsq
// ---------------------------------------------------------------------------
__global__ __launch_bounds__(256)
void stats_kernel(const float* __restrict__ x, float* __restrict__ sums, int N)
{
    __shared__ float s_s[256];
    __shared__ float s_q[256];
    const int d = threadIdx.x & 63;
    const int g = threadIdx.x >> 6;
    float s = 0.f, q = 0.f;
    for (int n = blockIdx.x * 4 + g; n < N; n += gridDim.x * 4) {
        const float v = x[(size_t)n * CCH + d];
        s += v;
        q += v * v;
    }
    s_s[threadIdx.x] = s;
    s_q[threadIdx.x] = q;
    __syncthreads();
    if (threadIdx.x < 64) {
        s = s_s[d] + s_s[64 + d] + s_s[128 + d] + s_s[192 + d];
        q = s_q[d] + s_q[64 + d] + s_q[128 + d] + s_q[192 + d];
        atomicAdd(&sums[d], s);
        atomicAdd(&sums[64 + d], q);
    }
}

// ---------------------------------------------------------------------------
// In-place BN + ReLU over [N, C], float4 (4 consecutive channels per thread)
// ---------------------------------------------------------------------------
__global__ __launch_bounds__(256)
void bn_relu_kernel(float* __restrict__ x, const float* __restrict__ sums,
                    const float* __restrict__ gmm, const float* __restrict__ bet,
                    float invN, int total4)
{
    const int idx = blockIdx.x * blockDim.x + threadIdx.x;
    if (idx >= total4) return;
    float4 v = reinterpret_cast<float4*>(x)[idx];
    const int c0 = (idx & 15) * 4;
    float sc[4], sh[4];
#pragma unroll
    for (int i = 0; i < 4; ++i) {
        const int c = c0 + i;
        const float mu  = sums[c] * invN;
        const float var = sums[64 + c] * invN - mu * mu;
        const float rs  = rsqrtf(var + EPSV);
        sc[i] = gmm[c] * rs;
        sh[i] = bet[c] - mu * sc[i];
    }
    v.x = fmaxf(fmaf(v.x, sc[0], sh[0]), 0.f);
    v.y = fmaxf(fmaf(v.y, sc[1], sh[1]), 0.f);
    v.z = fmaxf(fmaf(v.z, sc[2], sh[2]), 0.f);
    v.w = fmaxf(fmaf(v.w, sc[3], sh[3]), 0.f);
    reinterpret_cast<float4*>(x)[idx] = v;
}

// ---------------------------------------------------------------------------
// In-place BN + residual add + ReLU:  x = relu(bn(x) + feats)
// ---------------------------------------------------------------------------
__global__ __launch_bounds__(256)
void bn_res_relu_kernel(float* __restrict__ x, const float* __restrict__ feats,
                        const float* __restrict__ sums, const float* __restrict__ gmm,
                        const float* __restrict__ bet, float invN, int total4)
{
    const int idx = blockIdx.x * blockDim.x + threadIdx.x;
    if (idx >= total4) return;
    float4 v = reinterpret_cast<float4*>(x)[idx];
    const float4 f = reinterpret_cast<const float4*>(feats)[idx];
    const int c0 = (idx & 15) * 4;
    float sc[4], sh[4];
#pragma unroll
    for (int i = 0; i < 4; ++i) {
        const int c = c0 + i;
        const float mu  = sums[c] * invN;
        const float var = sums[64 + c] * invN - mu * mu;
        const float rs  = rsqrtf(var + EPSV);
        sc[i] = gmm[c] * rs;
        sh[i] = bet[c] - mu * sc[i];
    }
    v.x = fmaxf(fmaf(v.x, sc[0], sh[0]) + f.x, 0.f);
    v.y = fmaxf(fmaf(v.y, sc[1], sh[1]) + f.y, 0.f);
    v.z = fmaxf(fmaf(v.z, sc[2], sh[2]) + f.z, 0.f);
    v.w = fmaxf(fmaf(v.w, sc[3], sh[3]) + f.w, 0.f);
    reinterpret_cast<float4*>(x)[idx] = v;
}

extern "C" void kernel_launch(void* const* d_in, const int* in_sizes, int n_in,
                              void* d_out, int out_size, void* d_ws, size_t ws_size,
                              hipStream_t stream)
{
    const float* feats = (const float*)d_in[0];
    const int*   nbr   = (const int*)d_in[1];
    const float* W1    = (const float*)d_in[2];
    const float* b1    = (const float*)d_in[3];
    const float* g1    = (const float*)d_in[4];
    const float* be1   = (const float*)d_in[5];
    const float* W2    = (const float*)d_in[6];
    const float* b2    = (const float*)d_in[7];
    const float* g2    = (const float*)d_in[8];
    const float* be2   = (const float*)d_in[9];
    float* out = (float*)d_out;

    const int N = in_sizes[0] / CCH;        // 100000
    const float invN = 1.0f / (float)N;

    float* h0    = (float*)d_ws;             // [N, C] hidden after conv1+bn1+relu
    float* stats = h0 + (size_t)N * CCH;     // stats1[128] then stats2[128]

    hipMemsetAsync(stats, 0, 256 * sizeof(float), stream);

    const int convGrid = (N + 4 * NV - 1) / (4 * NV);
    const int ewGrid   = (N * (CCH / 4) + 255) / 256;

    conv_kernel<<<convGrid, 256, 0, stream>>>(feats, nbr, W1, b1, h0, N);
    stats_kernel<<<512, 256, 0, stream>>>(h0, stats, N);
    bn_relu_kernel<<<ewGrid, 256, 0, stream>>>(h0, stats, g1, be1, invN, N * (CCH / 4));
    conv_kernel<<<convGrid, 256, 0, stream>>>(h0, nbr, W2, b2, out, N);
    stats_kernel<<<512, 256, 0, stream>>>(out, stats + 128, N);
    bn_res_relu_kernel<<<ewGrid, 256, 0, stream>>>(out, feats, stats + 128, g2, be2,
                                                   invN, N * (CCH / 4));
}

// Round 2
// 311.441 us; speedup vs baseline: 14.7985x; 14.7985x over previous
//
#include <hip/hip_runtime.h>

#define NCH 64      // channels
#define KOFF 27     // kernel offsets
#define EPSV 1e-5f

typedef __attribute__((ext_vector_type(8))) short  bf16x8;
typedef __attribute__((ext_vector_type(4))) float  f32x4;
typedef __attribute__((ext_vector_type(8))) unsigned short u16x8;

__device__ __forceinline__ unsigned short f2bf(float x) {
    unsigned int u = __float_as_uint(x);
    u += 0x7fffu + ((u >> 16) & 1u);       // round-to-nearest-even
    return (unsigned short)(u >> 16);
}

// ---------------------------------------------------------------------------
// fp32 -> bf16 cast, 8 elements/thread
// ---------------------------------------------------------------------------
__global__ __launch_bounds__(256)
void cast_bf16_kernel(const float* __restrict__ x, unsigned short* __restrict__ y,
                      int total8)
{
    const int idx = blockIdx.x * 256 + threadIdx.x;
    if (idx >= total8) return;
    const float4* xp = reinterpret_cast<const float4*>(x) + (size_t)idx * 2;
    const float4 a = xp[0], b = xp[1];
    u16x8 o;
    o[0] = f2bf(a.x); o[1] = f2bf(a.y); o[2] = f2bf(a.z); o[3] = f2bf(a.w);
    o[4] = f2bf(b.x); o[5] = f2bf(b.y); o[6] = f2bf(b.z); o[7] = f2bf(b.w);
    reinterpret_cast<u16x8*>(y)[idx] = o;
}

// ---------------------------------------------------------------------------
// W[k][c][d] fp32 -> Wt in B-fragment order, bf16:
//   Wt[(((k*2+s)*4+ct)*64+lane)*8 + j] = W[k][s*32+(lane>>4)*8+j][ct*16+(lane&15)]
// 13824 threads total (54 blocks x 256).
// ---------------------------------------------------------------------------
__global__ __launch_bounds__(256)
void wtrans_kernel(const float* __restrict__ W, unsigned short* __restrict__ Wt)
{
    const int t  = blockIdx.x * 256 + threadIdx.x;   // 0..13823
    const int l  = t & 63;
    const int ct = (t >> 6) & 3;
    const int s  = (t >> 8) & 1;
    const int k  = t >> 9;
    const int d     = ct * 16 + (l & 15);
    const int cbase = s * 32 + (l >> 4) * 8;
    u16x8 o;
#pragma unroll
    for (int j = 0; j < 8; ++j)
        o[j] = f2bf(W[(size_t)k * 4096 + (size_t)(cbase + j) * 64 + d]);
    reinterpret_cast<u16x8*>(Wt)[t] = o;
}

// ---------------------------------------------------------------------------
// Gathered conv via MFMA 16x16x32 bf16.
// Block = 4 waves = 64 voxels x 64 out-channels. Wave w: voxels w*16..w*16+15.
// Per offset k: gather 64 bf16 rows into LDS (double-buffered, row stride 72
// to break bank aliasing), stage Wt slice (8KB), 8 MFMAs per wave.
// ---------------------------------------------------------------------------
__global__ __launch_bounds__(256, 3)
void conv_mfma_kernel(const unsigned short* __restrict__ fin,
                      const int* __restrict__ nbr,
                      const unsigned short* __restrict__ Wt,
                      const float* __restrict__ bias,
                      float* __restrict__ out, int N)
{
    __shared__ int s_idx[64 * KOFF];
    __shared__ unsigned short sA[2][64 * 72];
    __shared__ unsigned short sB[2][4096];

    const int t    = threadIdx.x;
    const int lane = t & 63;
    const int w    = t >> 6;
    const int n0   = blockIdx.x * 64;

    {   // stage neighbor indices for this block's 64 voxels (coalesced)
        const int* nb  = nbr + (size_t)n0 * KOFF;
        const int rem  = N - n0;
        const int maxi = (rem < 64 ? rem : 64) * KOFF;
        for (int i = t; i < 64 * KOFF; i += 256)
            s_idx[i] = (i < maxi) ? nb[i] : 0;
    }
    __syncthreads();

    auto stage = [&](int k, int b) {
        // A-tile: 64 rows x 128B, 512 chunks of 16B, 2 per thread
#pragma unroll
        for (int h = 0; h < 2; ++h) {
            const int q = t + h * 256;
            const int v = q >> 3, p = q & 7;
            const int ridx = s_idx[v * KOFF + k];
            const uint4 d = *reinterpret_cast<const uint4*>(
                fin + (size_t)ridx * NCH + p * 8);
            *reinterpret_cast<uint4*>(&sA[b][v * 72 + p * 8]) = d;
        }
        // B-tile: contiguous 8KB slice of Wt
        const unsigned short* src = Wt + (size_t)k * 4096;
#pragma unroll
        for (int h = 0; h < 2; ++h) {
            const int q = t + h * 256;
            const uint4 d = *reinterpret_cast<const uint4*>(src + q * 8);
            *reinterpret_cast<uint4*>(&sB[b][q * 8]) = d;
        }
    };

    f32x4 acc[4];
#pragma unroll
    for (int ct = 0; ct < 4; ++ct) acc[ct] = (f32x4){0.f, 0.f, 0.f, 0.f};

    stage(0, 0);
    __syncthreads();

    const int m    = lane & 15;
    const int quad = lane >> 4;

    for (int k = 0; k < KOFF; ++k) {
        const int cur = k & 1;
        if (k + 1 < KOFF) stage(k + 1, cur ^ 1);

        const unsigned short* Ab = &sA[cur][(w * 16 + m) * 72 + quad * 8];
#pragma unroll
        for (int s = 0; s < 2; ++s) {
            const bf16x8 a = *reinterpret_cast<const bf16x8*>(Ab + s * 32);
#pragma unroll
            for (int ct = 0; ct < 4; ++ct) {
                const bf16x8 bb = *reinterpret_cast<const bf16x8*>(
                    &sB[cur][((s * 4 + ct) * 64 + lane) * 8]);
                acc[ct] = __builtin_amdgcn_mfma_f32_16x16x32_bf16(a, bb, acc[ct], 0, 0, 0);
            }
        }
        __syncthreads();
    }

    // epilogue: D layout col=lane&15, row=quad*4+reg
#pragma unroll
    for (int ct = 0; ct < 4; ++ct) {
        const int ch = ct * 16 + m;
        const float bv = bias[ch];
#pragma unroll
        for (int r = 0; r < 4; ++r) {
            const int vox = n0 + w * 16 + quad * 4 + r;
            if (vox < N) out[(size_t)vox * NCH + ch] = acc[ct][r] + bv;
        }
    }
}

// ---------------------------------------------------------------------------
// Per-channel sum / sum-of-squares
// ---------------------------------------------------------------------------
__global__ __launch_bounds__(256)
void stats_kernel(const float* __restrict__ x, float* __restrict__ sums, int N)
{
    __shared__ float s_s[256];
    __shared__ float s_q[256];
    const int d = threadIdx.x & 63;
    const int g = threadIdx.x >> 6;
    float s = 0.f, q = 0.f;
    for (int n = blockIdx.x * 4 + g; n < N; n += gridDim.x * 4) {
        const float v = x[(size_t)n * NCH + d];
        s += v;
        q += v * v;
    }
    s_s[threadIdx.x] = s;
    s_q[threadIdx.x] = q;
    __syncthreads();
    if (threadIdx.x < 64) {
        s = s_s[d] + s_s[64 + d] + s_s[128 + d] + s_s[192 + d];
        q = s_q[d] + s_q[64 + d] + s_q[128 + d] + s_q[192 + d];
        atomicAdd(&sums[d], s);
        atomicAdd(&sums[64 + d], q);
    }
}

// ---------------------------------------------------------------------------
// BN + ReLU, fp32 in -> bf16 out (conv2's gather input). 8 elems/thread.
// ---------------------------------------------------------------------------
__global__ __launch_bounds__(256)
void bn_relu_bf16_kernel(const float* __restrict__ x, const float* __restrict__ sums,
                         const float* __restrict__ gmm, const float* __restrict__ bet,
                         float invN, unsigned short* __restrict__ y, int total8)
{
    const int idx = blockIdx.x * 256 + threadIdx.x;
    if (idx >= total8) return;
    const int c0 = (idx & 7) * 8;
    const float4* xp = reinterpret_cast<const float4*>(x) + (size_t)idx * 2;
    const float4 a = xp[0], b = xp[1];
    float v[8] = {a.x, a.y, a.z, a.w, b.x, b.y, b.z, b.w};
    u16x8 o;
#pragma unroll
    for (int i = 0; i < 8; ++i) {
        const int c = c0 + i;
        const float mu  = sums[c] * invN;
        const float var = sums[64 + c] * invN - mu * mu;
        const float rs  = rsqrtf(var + EPSV);
        const float sc  = gmm[c] * rs;
        const float sh  = bet[c] - mu * sc;
        o[i] = f2bf(fmaxf(fmaf(v[i], sc, sh), 0.f));
    }
    reinterpret_cast<u16x8*>(y)[idx] = o;
}

// ---------------------------------------------------------------------------
// BN + residual + ReLU, in-place fp32 (final output)
// ---------------------------------------------------------------------------
__global__ __launch_bounds__(256)
void bn_res_relu_kernel(float* __restrict__ x, const float* __restrict__ feats,
                        const float* __restrict__ sums, const float* __restrict__ gmm,
                        const float* __restrict__ bet, float invN, int total4)
{
    const int idx = blockIdx.x * blockDim.x + threadIdx.x;
    if (idx >= total4) return;
    float4 v = reinterpret_cast<float4*>(x)[idx];
    const float4 f = reinterpret_cast<const float4*>(feats)[idx];
    const int c0 = (idx & 15) * 4;
    float sc[4], sh[4];
#pragma unroll
    for (int i = 0; i < 4; ++i) {
        const int c = c0 + i;
        const float mu  = sums[c] * invN;
        const float var = sums[64 + c] * invN - mu * mu;
        const float rs  = rsqrtf(var + EPSV);
        sc[i] = gmm[c] * rs;
        sh[i] = bet[c] - mu * sc[i];
    }
    v.x = fmaxf(fmaf(v.x, sc[0], sh[0]) + f.x, 0.f);
    v.y = fmaxf(fmaf(v.y, sc[1], sh[1]) + f.y, 0.f);
    v.z = fmaxf(fmaf(v.z, sc[2], sh[2]) + f.z, 0.f);
    v.w = fmaxf(fmaf(v.w, sc[3], sh[3]) + f.w, 0.f);
    reinterpret_cast<float4*>(x)[idx] = v;
}

extern "C" void kernel_launch(void* const* d_in, const int* in_sizes, int n_in,
                              void* d_out, int out_size, void* d_ws, size_t ws_size,
                              hipStream_t stream)
{
    const float* feats = (const float*)d_in[0];
    const int*   nbr   = (const int*)d_in[1];
    const float* W1    = (const float*)d_in[2];
    const float* b1    = (const float*)d_in[3];
    const float* g1    = (const float*)d_in[4];
    const float* be1   = (const float*)d_in[5];
    const float* W2    = (const float*)d_in[6];
    const float* b2    = (const float*)d_in[7];
    const float* g2    = (const float*)d_in[8];
    const float* be2   = (const float*)d_in[9];
    float* out = (float*)d_out;

    const int N  = in_sizes[0] / NCH;          // 100000
    const int NC = N * NCH;                    // 6,400,000
    const float invN = 1.0f / (float)N;

    // workspace layout
    float*          h0   = (float*)d_ws;                       // [N*C] fp32
    unsigned short* fbf  = (unsigned short*)(h0 + NC);         // [N*C] bf16
    unsigned short* hbf  = fbf + NC;                           // [N*C] bf16
    unsigned short* wt1  = hbf + NC;                           // 110592 bf16
    unsigned short* wt2  = wt1 + KOFF * 4096;                  // 110592 bf16
    float*          stat = (float*)(wt2 + KOFF * 4096);        // 256 fp32

    hipMemsetAsync(stat, 0, 256 * sizeof(float), stream);

    const int total8   = NC / 8;                               // 800000
    const int castGrid = (total8 + 255) / 256;                 // 3125
    const int convGrid = (N + 63) / 64;                        // 1563
    const int ewGrid   = (NC / 4 + 255) / 256;                 // 6250

    cast_bf16_kernel<<<castGrid, 256, 0, stream>>>(feats, fbf, total8);
    wtrans_kernel<<<KOFF * 512 / 256, 256, 0, stream>>>(W1, wt1);   // 54 blocks
    wtrans_kernel<<<KOFF * 512 / 256, 256, 0, stream>>>(W2, wt2);

    conv_mfma_kernel<<<convGrid, 256, 0, stream>>>(fbf, nbr, wt1, b1, h0, N);
    stats_kernel<<<512, 256, 0, stream>>>(h0, stat, N);
    bn_relu_bf16_kernel<<<castGrid, 256, 0, stream>>>(h0, stat, g1, be1, invN,
                                                      hbf, total8);
    conv_mfma_kernel<<<convGrid, 256, 0, stream>>>(hbf, nbr, wt2, b2, out, N);
    stats_kernel<<<512, 256, 0, stream>>>(out, stat + 128, N);
    bn_res_relu_kernel<<<ewGrid, 256, 0, stream>>>(out, feats, stat + 128, g2, be2,
                                                   invN, NC / 4);
}